// Round 8
// baseline (215.302 us; speedup 1.0000x reference)
//
#include <hip/hip_runtime.h>
#include <hip/hip_bf16.h>
#include <hip/hip_fp16.h>
#include <math.h>

// ---- problem constants ----
#define BQ 2
#define LQ 13294
#define LEN_IN 13294
#define M_ROWS 26588          // BQ*LQ

__device__ __constant__ int c_HW[4]    = {100, 50, 25, 13};
__device__ __constant__ int c_START[4] = {0, 10000, 12500, 13125};

typedef __attribute__((ext_vector_type(8))) short bf16x8;
typedef __attribute__((ext_vector_type(4))) float f32x4;
typedef __attribute__((ext_vector_type(2))) float f32x2;

__device__ inline unsigned short f2bf(float f) {
  union { float f; unsigned int u; } x; x.f = f;
  unsigned int u = x.u;
  return (unsigned short)((u + 0x7fffu + ((u >> 16) & 1u)) >> 16);
}
__device__ inline float h2f(unsigned short h) {
  _Float16 x; __builtin_memcpy(&x, &h, 2); return (float)x;
}
__device__ inline unsigned int pk_bf16(float lo, float hi) {
  __hip_bfloat162 h = __float22bfloat162_rn(make_float2(lo, hi));
  unsigned int u; __builtin_memcpy(&u, &h, 4); return u;
}
__device__ inline unsigned int pk_f16(float lo, float hi) {
  __half2 h = __float22half2_rn(make_float2(lo, hi));
  unsigned int u; __builtin_memcpy(&u, &h, 4); return u;
}

__device__ inline void gl_lds16(const void* g, void* l) {
  __builtin_amdgcn_global_load_lds(
      (const __attribute__((address_space(1))) unsigned int*)g,
      (__attribute__((address_space(3))) unsigned int*)l, 16, 0, 0);
}

// convert 8 consecutive fp32 -> bf16x8 fragment (packed cvt)
__device__ inline bf16x8 cvt8(const float* p) {
  const float4 a = *(const float4*)p;
  const float4 b = *(const float4*)(p + 4);
  union { unsigned int u[4]; bf16x8 v; } r;
  r.u[0] = pk_bf16(a.x, a.y);
  r.u[1] = pk_bf16(a.z, a.w);
  r.u[2] = pk_bf16(b.x, b.y);
  r.u[3] = pk_bf16(b.z, b.w);
  return r.v;
}

// ---------------------------------------------------------------------------
// Weight prep: transpose + convert to bf16 [N][K] + fused oa bias.
// ---------------------------------------------------------------------------
__global__ __launch_bounds__(256) void prep_w(
    const float* __restrict__ W_off, const float* __restrict__ b_off,
    const float* __restrict__ W_attn, const float* __restrict__ b_attn,
    const float* __restrict__ W_val, const float* __restrict__ W_out,
    unsigned short* __restrict__ Wval_t, unsigned short* __restrict__ Woa_t,
    unsigned short* __restrict__ Wout_t, float* __restrict__ b_oa) {
  const int idx = blockIdx.x * 256 + threadIdx.x;
  const int SZ1 = 256 * 256;
  const int SZ2 = 384 * 256;
  if (idx < SZ1) {
    const int n = idx >> 8, k = idx & 255;
    Wval_t[idx] = f2bf(W_val[k * 256 + n]);
  } else if (idx < SZ1 + SZ2) {
    const int j = idx - SZ1;
    const int n = j >> 8, k = j & 255;
    const float v = (n < 256) ? W_off[k * 256 + n] : W_attn[k * 128 + (n - 256)];
    Woa_t[j] = f2bf(v);
  } else {
    const int j = idx - SZ1 - SZ2;
    const int n = j >> 8, k = j & 255;
    Wout_t[j] = f2bf(W_out[k * 256 + n]);
  }
  if (blockIdx.x == 0) b_oa[threadIdx.x] = b_off[threadIdx.x];
  if (blockIdx.x == 1 && threadIdx.x < 128)
    b_oa[256 + threadIdx.x] = b_attn[threadIdx.x];
}

// ---------------------------------------------------------------------------
// n-tile-fused streaming GEMMs. A block owns a 64-row m-slice (wave = one
// 16-row MFMA tile), preloads A fragments to registers ONCE, then iterates
// (matrix, n-tile) jobs re-staging only the 64 KB weight slice per job.
// operand-swapped mfma(b,a,acc): lane&15 = m, (lane>>4)*4+reg = 4 consecutive
// n -> vectorized stores. A is read exactly once from HBM.
// ---------------------------------------------------------------------------
__device__ inline void stage_W(const unsigned short* __restrict__ Wt,
                               int n0, int wv, int lane, unsigned short* Ws) {
#pragma unroll
  for (int it = 0; it < 16; ++it) {
    const int lin = wv * 1024 + it * 64 + lane;   // 16B-chunk linear index
    const int r = lin >> 5;                        // W row 0..127
    const int p = lin & 31;                        // physical chunk in row
    const int c = p ^ (r & 7);                     // logical chunk fetched
    gl_lds16(Wt + (size_t)(n0 + r) * 256 + c * 8,
             &Ws[(size_t)(wv * 1024 + it * 64) * 8]);
  }
}

// CT: 0 = fp32 C, 1 = bf16 C, 2 = fp16 C.
template <int CT>
__device__ inline void run_job(const bf16x8* af,
                               const unsigned short* __restrict__ Wt,
                               const float* __restrict__ bias,
                               void* __restrict__ Cp, int N, int n0,
                               int m, int wv, int lane, int fr, int fq,
                               unsigned short* Ws) {
  __syncthreads();                 // prior job's Ws readers done
  stage_W(Wt, n0, wv, lane, Ws);
  __syncthreads();                 // DMA complete

  f32x4 acc[8];
#pragma unroll
  for (int n = 0; n < 8; ++n) acc[n] = (f32x4){0.f, 0.f, 0.f, 0.f};

#pragma unroll
  for (int kk = 0; kk < 8; ++kk) {
#pragma unroll
    for (int n = 0; n < 8; ++n) {
      const int rn = n * 16 + fr;
      const bf16x8 b =
          *(const bf16x8*)&Ws[rn * 256 + (((kk * 4 + fq) ^ (rn & 7)) * 8)];
      acc[n] = __builtin_amdgcn_mfma_f32_16x16x32_bf16(b, af[kk], acc[n], 0, 0, 0);
    }
  }

  if (m < M_ROWS) {
#pragma unroll
    for (int n = 0; n < 8; ++n) {
      const int nb = n0 + n * 16 + fq * 4;
      const float4 b4 = *(const float4*)&bias[nb];
      const float v0 = acc[n][0] + b4.x;
      const float v1 = acc[n][1] + b4.y;
      const float v2 = acc[n][2] + b4.z;
      const float v3 = acc[n][3] + b4.w;
      if (CT == 0) {
        *(float4*)&((float*)Cp)[(size_t)m * N + nb] = make_float4(v0, v1, v2, v3);
      } else if (CT == 1) {
        uint2 o; o.x = pk_bf16(v0, v1); o.y = pk_bf16(v2, v3);
        *(uint2*)&((unsigned short*)Cp)[(size_t)m * N + nb] = o;
      } else {
        uint2 o; o.x = pk_f16(v0, v1); o.y = pk_f16(v2, v3);
        *(uint2*)&((unsigned short*)Cp)[(size_t)m * N + nb] = o;
      }
    }
  }
}

// value (inpf @ Wval -> bf16, n-tiles 0,128) + oa (query @ Woa -> fp16,
// n-tiles 0,128,256) in one launch; A slices read once.
__global__ __launch_bounds__(256) void gemm_mlp(
    const float* __restrict__ inpf, const float* __restrict__ query,
    const unsigned short* __restrict__ Wval_t,
    const unsigned short* __restrict__ Woa_t,
    const float* __restrict__ b_val, const float* __restrict__ b_oa,
    void* __restrict__ v_buf, void* __restrict__ oa_buf) {
  __shared__ unsigned short Ws[128 * 256];
  const int tid = threadIdx.x;
  const int wv = tid >> 6;
  const int lane = tid & 63;
  const int fr = lane & 15;
  const int fq = lane >> 4;
  const int m = blockIdx.x * 64 + wv * 16 + fr;
  const int mr = (m > M_ROWS - 1) ? (M_ROWS - 1) : m;

  const float* ain = inpf + (size_t)mr * 256 + fq * 8;
  const float* aq  = query + (size_t)mr * 256 + fq * 8;
  bf16x8 fin[8], fqr[8];
#pragma unroll
  for (int kk = 0; kk < 8; ++kk) fin[kk] = cvt8(ain + kk * 32);
#pragma unroll
  for (int kk = 0; kk < 8; ++kk) fqr[kk] = cvt8(aq + kk * 32);

  run_job<1>(fin, Wval_t, b_val, v_buf, 256, 0,   m, wv, lane, fr, fq, Ws);
  run_job<1>(fin, Wval_t, b_val, v_buf, 256, 128, m, wv, lane, fr, fq, Ws);
  run_job<2>(fqr, Woa_t, b_oa, oa_buf, 384, 0,   m, wv, lane, fr, fq, Ws);
  run_job<2>(fqr, Woa_t, b_oa, oa_buf, 384, 128, m, wv, lane, fr, fq, Ws);
  run_job<2>(fqr, Woa_t, b_oa, oa_buf, 384, 256, m, wv, lane, fr, fq, Ws);
}

__global__ __launch_bounds__(256) void gemm_out(
    const unsigned short* __restrict__ mid,
    const unsigned short* __restrict__ Wout_t,
    const float* __restrict__ b_out, float* __restrict__ out) {
  __shared__ unsigned short Ws[128 * 256];
  const int tid = threadIdx.x;
  const int wv = tid >> 6;
  const int lane = tid & 63;
  const int fr = lane & 15;
  const int fq = lane >> 4;
  const int m = blockIdx.x * 64 + wv * 16 + fr;
  const int mr = (m > M_ROWS - 1) ? (M_ROWS - 1) : m;

  const unsigned short* a = mid + (size_t)mr * 256 + fq * 8;
  bf16x8 af[8];
#pragma unroll
  for (int kk = 0; kk < 8; ++kk) af[kk] = *(const bf16x8*)(a + kk * 32);

  run_job<0>(af, Wout_t, b_out, out, 256, 0,   m, wv, lane, fr, fq, Ws);
  run_job<0>(af, Wout_t, b_out, out, 256, 128, m, wv, lane, fr, fq, Ws);
}

// ---------------------------------------------------------------------------
// Sampler (R4-proven structure, unchanged): 2 queries/block, 256 threads.
// ---------------------------------------------------------------------------
__global__ __launch_bounds__(256) void sample_kernel(
    const float* __restrict__ refp,           // (B,LQ,4,2) fp32
    const unsigned short* __restrict__ oa,    // (M,384) fp16: off|logits
    const unsigned short* __restrict__ value, // (M,256) bf16
    unsigned int* __restrict__ mid) {         // (M,128) u32 bf16-pairs
  const int tid = threadIdx.x;
  const int qi = tid >> 7;
  const int q = blockIdx.x * 2 + qi;
  const int b = (q >= LQ) ? 1 : 0;

  __shared__ float2 s_wo[2][4][136];          // [qi][tap][h*17+lp]

  // ---- Phase A ----
  {
    const int pid = tid & 127;                // h*16 + l*4 + p
    const int h = pid >> 4;
    const int lp = pid & 15;
    const int l = lp >> 2;
    const int p = lp & 3;
    const int HW = c_HW[l];
    const float fW = (float)HW;

    const float logit = h2f(oa[(size_t)q * 384 + 256 + pid]);
    float mx = logit;
#pragma unroll
    for (int s = 1; s < 16; s <<= 1) mx = fmaxf(mx, __shfl_xor(mx, s, 16));
    const float e = expf(logit - mx);
    float sum = e;
#pragma unroll
    for (int s = 1; s < 16; s <<= 1) sum += __shfl_xor(sum, s, 16);
    const float a = e / sum;

    const unsigned int opk =
        *(const unsigned int*)&oa[(size_t)q * 384 + h * 32 + l * 8 + p * 2];
    const float ox = h2f((unsigned short)(opk & 0xffffu));
    const float oy = h2f((unsigned short)(opk >> 16));
    const float rx = refp[((size_t)q * 4 + l) * 2 + 0];
    const float ry = refp[((size_t)q * 4 + l) * 2 + 1];
    const float x = fmaf(rx, fW, ox - 0.5f);
    const float y = fmaf(ry, fW, oy - 0.5f);
    const float x0 = floorf(x);
    const float y0 = floorf(y);

#pragma unroll
    for (int t = 0; t < 4; ++t) {
      const int dx = t & 1;
      const int dy = t >> 1;
      const float xi = x0 + (float)dx;
      const float yi = y0 + (float)dy;
      const float wgt = (1.0f - fabsf(x - xi)) * (1.0f - fabsf(y - yi));
      const bool valid =
          (xi >= 0.f) && (xi <= fW - 1.f) && (yi >= 0.f) && (yi <= fW - 1.f);
      int xc = (int)xi; xc = xc < 0 ? 0 : (xc > HW - 1 ? HW - 1 : xc);
      int yc = (int)yi; yc = yc < 0 ? 0 : (yc > HW - 1 ? HW - 1 : yc);
      const int row = b * LEN_IN + c_START[l] + yc * HW + xc;
      float2 wo;
      wo.x = valid ? wgt * a : 0.f;
      wo.y = __int_as_float(row * 512 + h * 64);  // bf16 row = 512 B
      s_wo[qi][t][h * 17 + lp] = wo;
    }
  }
  __syncthreads();

  // ---- Phase B ----
  {
    const int g = tid & 127;
    const int h = g >> 4;
    const int dp = g & 15;                    // d-pair
    const char* vbase = (const char*)value + dp * 4;
    f32x2 acc = {0.f, 0.f};
#pragma unroll 4
    for (int lp = 0; lp < 16; ++lp) {
      const int si = h * 17 + lp;
#pragma unroll
      for (int t = 0; t < 4; ++t) {
        const float2 f = s_wo[qi][t][si];
        const unsigned int v = *(const unsigned int*)(vbase + __float_as_int(f.y));
        f32x2 av = {__uint_as_float(v << 16), __uint_as_float(v & 0xffff0000u)};
        acc += f.x * av;
      }
    }
    mid[(size_t)q * 128 + h * 16 + dp] = pk_bf16(acc.x, acc.y);
  }
}

// ---------------------------------------------------------------------------
extern "C" void kernel_launch(void* const* d_in, const int* in_sizes, int n_in,
                              void* d_out, int out_size, void* d_ws,
                              size_t ws_size, hipStream_t stream) {
  const float* query  = (const float*)d_in[0];
  const float* refp   = (const float*)d_in[1];
  const float* inpf   = (const float*)d_in[2];
  const float* W_off  = (const float*)d_in[5];
  const float* b_off  = (const float*)d_in[6];
  const float* W_attn = (const float*)d_in[7];
  const float* b_attn = (const float*)d_in[8];
  const float* W_val  = (const float*)d_in[9];
  const float* b_val  = (const float*)d_in[10];
  const float* W_out  = (const float*)d_in[11];
  const float* b_out  = (const float*)d_in[12];
  float* out = (float*)d_out;

  unsigned char* w = (unsigned char*)d_ws;
  unsigned short* Wval_t = (unsigned short*)w;  w += 256 * 256 * 2;
  unsigned short* Woa_t  = (unsigned short*)w;  w += 384 * 256 * 2;
  unsigned short* Wout_t = (unsigned short*)w;  w += 256 * 256 * 2;
  float*          b_oa   = (float*)w;           w += 384 * 4 + 64;
  unsigned short* v_buf  = (unsigned short*)w;  w += (size_t)M_ROWS * 256 * 2;
  unsigned short* oa_buf = (unsigned short*)w;  w += (size_t)M_ROWS * 384 * 2;
  unsigned int*   mid_buf = (unsigned int*)w;   // M*128 u32

  const dim3 blk(256);
  const int mg64 = (M_ROWS + 63) / 64;   // 416

  prep_w<<<dim3(896), blk, 0, stream>>>(W_off, b_off, W_attn, b_attn,
                                        W_val, W_out, Wval_t, Woa_t,
                                        Wout_t, b_oa);
  // value -> bf16 ; off|logits -> fp16 (A read once, 5 n-tile jobs)
  gemm_mlp<<<dim3(mg64), blk, 0, stream>>>(inpf, query, Wval_t, Woa_t,
                                           b_val, b_oa, v_buf, oa_buf);
  // softmax + bilinear sampling -> mid (bf16 pairs)
  sample_kernel<<<dim3(M_ROWS / 2), blk, 0, stream>>>(refp, oa_buf, v_buf,
                                                      mid_buf);
  // out = mid @ W_out + b_out -> fp32 (A read once, 2 n-tile jobs)
  gemm_out<<<dim3(mg64), blk, 0, stream>>>((const unsigned short*)mid_buf,
                                           Wout_t, b_out, out);
}

// Round 9
// 207.032 us; speedup vs baseline: 1.0399x; 1.0399x over previous
//
#include <hip/hip_runtime.h>
#include <hip/hip_bf16.h>
#include <hip/hip_fp16.h>
#include <math.h>

// ---- problem constants ----
#define BQ 2
#define LQ 13294
#define LEN_IN 13294
#define M_ROWS 26588          // BQ*LQ

__device__ __constant__ int c_HW[4]    = {100, 50, 25, 13};
__device__ __constant__ int c_START[4] = {0, 10000, 12500, 13125};

typedef __attribute__((ext_vector_type(8))) short bf16x8;
typedef __attribute__((ext_vector_type(4))) float f32x4;
typedef __attribute__((ext_vector_type(2))) float f32x2;
typedef int int32x4 __attribute__((ext_vector_type(4)));

// raw buffer load (CK-style): SRD in SGPRs, 32-bit voffset -> 1 VALU addr/tap
__device__ int llvm_amdgcn_raw_buffer_load_i32(int32x4 srsrc, int voffset,
                                               int soffset, int glc)
    __asm("llvm.amdgcn.raw.buffer.load.i32");

__device__ inline unsigned short f2bf(float f) {
  union { float f; unsigned int u; } x; x.f = f;
  unsigned int u = x.u;
  return (unsigned short)((u + 0x7fffu + ((u >> 16) & 1u)) >> 16);
}
__device__ inline float h2f(unsigned short h) {
  _Float16 x; __builtin_memcpy(&x, &h, 2); return (float)x;
}
__device__ inline unsigned int pk_bf16(float lo, float hi) {
  __hip_bfloat162 h = __float22bfloat162_rn(make_float2(lo, hi));
  unsigned int u; __builtin_memcpy(&u, &h, 4); return u;
}
__device__ inline unsigned int pk_f16(float lo, float hi) {
  __half2 h = __float22half2_rn(make_float2(lo, hi));
  unsigned int u; __builtin_memcpy(&u, &h, 4); return u;
}

__device__ inline void gl_lds16(const void* g, void* l) {
  __builtin_amdgcn_global_load_lds(
      (const __attribute__((address_space(1))) unsigned int*)g,
      (__attribute__((address_space(3))) unsigned int*)l, 16, 0, 0);
}

// convert 8 consecutive fp32 -> bf16x8 fragment (packed cvt)
__device__ inline bf16x8 cvt8(const float* p) {
  const float4 a = *(const float4*)p;
  const float4 b = *(const float4*)(p + 4);
  union { unsigned int u[4]; bf16x8 v; } r;
  r.u[0] = pk_bf16(a.x, a.y);
  r.u[1] = pk_bf16(a.z, a.w);
  r.u[2] = pk_bf16(b.x, b.y);
  r.u[3] = pk_bf16(b.z, b.w);
  return r.v;
}

// ---------------------------------------------------------------------------
// Weight prep: transpose + convert to bf16 [N][K] + fused oa bias.
// ---------------------------------------------------------------------------
__global__ __launch_bounds__(256) void prep_w(
    const float* __restrict__ W_off, const float* __restrict__ b_off,
    const float* __restrict__ W_attn, const float* __restrict__ b_attn,
    const float* __restrict__ W_val, const float* __restrict__ W_out,
    unsigned short* __restrict__ Wval_t, unsigned short* __restrict__ Woa_t,
    unsigned short* __restrict__ Wout_t, float* __restrict__ b_oa) {
  const int idx = blockIdx.x * 256 + threadIdx.x;
  const int SZ1 = 256 * 256;
  const int SZ2 = 384 * 256;
  if (idx < SZ1) {
    const int n = idx >> 8, k = idx & 255;
    Wval_t[idx] = f2bf(W_val[k * 256 + n]);
  } else if (idx < SZ1 + SZ2) {
    const int j = idx - SZ1;
    const int n = j >> 8, k = j & 255;
    const float v = (n < 256) ? W_off[k * 256 + n] : W_attn[k * 128 + (n - 256)];
    Woa_t[j] = f2bf(v);
  } else {
    const int j = idx - SZ1 - SZ2;
    const int n = j >> 8, k = j & 255;
    Wout_t[j] = f2bf(W_out[k * 256 + n]);
  }
  if (blockIdx.x == 0) b_oa[threadIdx.x] = b_off[threadIdx.x];
  if (blockIdx.x == 1 && threadIdx.x < 128)
    b_oa[256 + threadIdx.x] = b_attn[threadIdx.x];
}

// ---------------------------------------------------------------------------
// Streaming GEMM (R7 best-measured structure): W slice (128x256 bf16, 64 KB)
// staged once in LDS (XOR-swizzled); A fragments preloaded to registers
// (fp32 variant converts in-register); single barrier; operand-swapped
// mfma(b,a,acc) -> vectorized epilogue stores.
// CT: 0 = fp32 C, 1 = bf16 C, 2 = fp16 C.
// ---------------------------------------------------------------------------
__device__ inline void stage_W(const unsigned short* __restrict__ Wt,
                               int n0, int wv, int lane, unsigned short* Ws) {
#pragma unroll
  for (int it = 0; it < 16; ++it) {
    const int lin = wv * 1024 + it * 64 + lane;   // 16B-chunk linear index
    const int r = lin >> 5;                        // W row 0..127
    const int p = lin & 31;                        // physical chunk in row
    const int c = p ^ (r & 7);                     // logical chunk fetched
    gl_lds16(Wt + (size_t)(n0 + r) * 256 + c * 8,
             &Ws[(size_t)(wv * 1024 + it * 64) * 8]);
  }
}

template <int CT>
__device__ inline void kloop_epilogue(
    const bf16x8* a0f, const bf16x8* a1f, const unsigned short* Ws,
    const float* __restrict__ bias, void* __restrict__ Cp,
    int M, int N, int m0, int n0, int wv, int fr, int fq) {
  f32x4 acc[2][8];
#pragma unroll
  for (int mt = 0; mt < 2; ++mt)
#pragma unroll
    for (int n = 0; n < 8; ++n) acc[mt][n] = (f32x4){0.f, 0.f, 0.f, 0.f};

#pragma unroll
  for (int kk = 0; kk < 8; ++kk) {
#pragma unroll
    for (int n = 0; n < 8; ++n) {
      const int rn = n * 16 + fr;
      const bf16x8 b =
          *(const bf16x8*)&Ws[rn * 256 + (((kk * 4 + fq) ^ (rn & 7)) * 8)];
      acc[0][n] = __builtin_amdgcn_mfma_f32_16x16x32_bf16(b, a0f[kk], acc[0][n], 0, 0, 0);
      acc[1][n] = __builtin_amdgcn_mfma_f32_16x16x32_bf16(b, a1f[kk], acc[1][n], 0, 0, 0);
    }
  }

#pragma unroll
  for (int n = 0; n < 8; ++n) {
    const int nb = n0 + n * 16 + fq * 4;
    const float4 b4 = *(const float4*)&bias[nb];
#pragma unroll
    for (int mt = 0; mt < 2; ++mt) {
      const int m = m0 + wv * 32 + mt * 16 + fr;
      if (m >= M) continue;
      const float v0 = acc[mt][n][0] + b4.x;
      const float v1 = acc[mt][n][1] + b4.y;
      const float v2 = acc[mt][n][2] + b4.z;
      const float v3 = acc[mt][n][3] + b4.w;
      if (CT == 0) {
        *(float4*)&((float*)Cp)[(size_t)m * N + nb] = make_float4(v0, v1, v2, v3);
      } else if (CT == 1) {
        uint2 o; o.x = pk_bf16(v0, v1); o.y = pk_bf16(v2, v3);
        *(uint2*)&((unsigned short*)Cp)[(size_t)m * N + nb] = o;
      } else {
        uint2 o; o.x = pk_f16(v0, v1); o.y = pk_f16(v2, v3);
        *(uint2*)&((unsigned short*)Cp)[(size_t)m * N + nb] = o;
      }
    }
  }
}

// fp32-A variant: loads A as float4 pairs, converts to bf16 fragments in regs.
template <int CT>
__device__ inline void gemm_stream_f32A(
    const float* __restrict__ A, const unsigned short* __restrict__ Wt,
    const float* __restrict__ bias, void* __restrict__ Cp,
    int M, int N, int m0, int n0, unsigned short* Ws) {
  const int tid = threadIdx.x;
  const int wv = tid >> 6;
  const int lane = tid & 63;
  const int fr = lane & 15;
  const int fq = lane >> 4;

  int mr0 = m0 + wv * 32 + fr;       if (mr0 > M - 1) mr0 = M - 1;
  int mr1 = m0 + wv * 32 + 16 + fr;  if (mr1 > M - 1) mr1 = M - 1;
  const float* a0 = A + (size_t)mr0 * 256 + fq * 8;
  const float* a1 = A + (size_t)mr1 * 256 + fq * 8;

  bf16x8 a0f[8], a1f[8];
#pragma unroll
  for (int kk = 0; kk < 8; ++kk) a0f[kk] = cvt8(a0 + kk * 32);
#pragma unroll
  for (int kk = 0; kk < 8; ++kk) a1f[kk] = cvt8(a1 + kk * 32);

  stage_W(Wt, n0, wv, lane, Ws);
  __syncthreads();   // the only barrier

  kloop_epilogue<CT>(a0f, a1f, Ws, bias, Cp, M, N, m0, n0, wv, fr, fq);
}

// bf16-A variant (for the out-projection; mid is already bf16).
template <int CT>
__device__ inline void gemm_stream_bf16A(
    const unsigned short* __restrict__ A, const unsigned short* __restrict__ Wt,
    const float* __restrict__ bias, void* __restrict__ Cp,
    int M, int N, int m0, int n0, unsigned short* Ws) {
  const int tid = threadIdx.x;
  const int wv = tid >> 6;
  const int lane = tid & 63;
  const int fr = lane & 15;
  const int fq = lane >> 4;

  int mr0 = m0 + wv * 32 + fr;       if (mr0 > M - 1) mr0 = M - 1;
  int mr1 = m0 + wv * 32 + 16 + fr;  if (mr1 > M - 1) mr1 = M - 1;
  const unsigned short* a0 = A + (size_t)mr0 * 256 + fq * 8;
  const unsigned short* a1 = A + (size_t)mr1 * 256 + fq * 8;
  bf16x8 a0f[8], a1f[8];
#pragma unroll
  for (int kk = 0; kk < 8; ++kk) {
    a0f[kk] = *(const bf16x8*)(a0 + kk * 32);
    a1f[kk] = *(const bf16x8*)(a1 + kk * 32);
  }

  stage_W(Wt, n0, wv, lane, Ws);
  __syncthreads();

  kloop_epilogue<CT>(a0f, a1f, Ws, bias, Cp, M, N, m0, n0, wv, fr, fq);
}

// value (y 0-1, A=input fp32, N=256, bf16 C) + oa (y 2-4, A=query fp32,
// N=384, fp16 C) fused.
__global__ __launch_bounds__(256) void gemm_vo(
    const float* __restrict__ inpf, const float* __restrict__ query,
    const unsigned short* __restrict__ Wval_t,
    const unsigned short* __restrict__ Woa_t,
    const float* __restrict__ b_val, const float* __restrict__ b_oa,
    void* __restrict__ v_buf, void* __restrict__ oa_buf) {
  __shared__ unsigned short Ws[128 * 256];
  const int m0 = blockIdx.x * 128;
  if (blockIdx.y < 2) {
    gemm_stream_f32A<1>(inpf, Wval_t, b_val, v_buf, M_ROWS, 256,
                        m0, blockIdx.y * 128, Ws);
  } else {
    gemm_stream_f32A<2>(query, Woa_t, b_oa, oa_buf, M_ROWS, 384,
                        m0, (blockIdx.y - 2) * 128, Ws);
  }
}

__global__ __launch_bounds__(256) void gemm_out(
    const unsigned short* __restrict__ mid,
    const unsigned short* __restrict__ Wout_t,
    const float* __restrict__ b_out, float* __restrict__ out) {
  __shared__ unsigned short Ws[128 * 256];
  gemm_stream_bf16A<0>(mid, Wout_t, b_out, out, M_ROWS, 256,
                       blockIdx.x * 128, blockIdx.y * 128, Ws);
}

// ---------------------------------------------------------------------------
// Sampler: 2 queries/block, 256 threads.
// Phase A: per-point softmax (16-lane shuffles) + tap {weight, byteoff} -> LDS
//   (float2, [tap][h*17+lp] layout -- zero bank conflicts measured).
// Phase B: 128 thr/query, thread owns (head, d-pair): 64 taps, each one
//   ds_read_b64 + one buffer_load_dword (SRD + 32-bit voffset: 1 VALU addr)
//   + packed f32x2 FMA.
// ---------------------------------------------------------------------------
__global__ __launch_bounds__(256) void sample_kernel(
    const float* __restrict__ refp,           // (B,LQ,4,2) fp32
    const unsigned short* __restrict__ oa,    // (M,384) fp16: off|logits
    const unsigned short* __restrict__ value, // (M,256) bf16
    unsigned int* __restrict__ mid) {         // (M,128) u32 bf16-pairs
  const int tid = threadIdx.x;
  const int qi = tid >> 7;
  const int q = blockIdx.x * 2 + qi;
  const int b = (q >= LQ) ? 1 : 0;

  __shared__ float2 s_wo[2][4][136];          // [qi][tap][h*17+lp]

  // ---- Phase A ----
  {
    const int pid = tid & 127;                // h*16 + l*4 + p
    const int h = pid >> 4;
    const int lp = pid & 15;
    const int l = lp >> 2;
    const int p = lp & 3;
    const int HW = c_HW[l];
    const float fW = (float)HW;

    const float logit = h2f(oa[(size_t)q * 384 + 256 + pid]);
    float mx = logit;
#pragma unroll
    for (int s = 1; s < 16; s <<= 1) mx = fmaxf(mx, __shfl_xor(mx, s, 16));
    const float e = expf(logit - mx);
    float sum = e;
#pragma unroll
    for (int s = 1; s < 16; s <<= 1) sum += __shfl_xor(sum, s, 16);
    const float a = e / sum;

    const unsigned int opk =
        *(const unsigned int*)&oa[(size_t)q * 384 + h * 32 + l * 8 + p * 2];
    const float ox = h2f((unsigned short)(opk & 0xffffu));
    const float oy = h2f((unsigned short)(opk >> 16));
    const float rx = refp[((size_t)q * 4 + l) * 2 + 0];
    const float ry = refp[((size_t)q * 4 + l) * 2 + 1];
    // (rx + ox/W)*W - 0.5 == rx*W + ox - 0.5
    const float x = fmaf(rx, fW, ox - 0.5f);
    const float y = fmaf(ry, fW, oy - 0.5f);
    const float x0 = floorf(x);
    const float y0 = floorf(y);

#pragma unroll
    for (int t = 0; t < 4; ++t) {
      const int dx = t & 1;
      const int dy = t >> 1;
      const float xi = x0 + (float)dx;
      const float yi = y0 + (float)dy;
      const float wgt = (1.0f - fabsf(x - xi)) * (1.0f - fabsf(y - yi));
      const bool valid =
          (xi >= 0.f) && (xi <= fW - 1.f) && (yi >= 0.f) && (yi <= fW - 1.f);
      int xc = (int)xi; xc = xc < 0 ? 0 : (xc > HW - 1 ? HW - 1 : xc);
      int yc = (int)yi; yc = yc < 0 ? 0 : (yc > HW - 1 ? HW - 1 : yc);
      const int row = b * LEN_IN + c_START[l] + yc * HW + xc;
      float2 wo;
      wo.x = valid ? wgt * a : 0.f;
      wo.y = __int_as_float(row * 512 + h * 64);  // bf16 row = 512 B
      s_wo[qi][t][h * 17 + lp] = wo;
    }
  }
  __syncthreads();

  // ---- Phase B ----
  {
    const int g = tid & 127;
    const int h = g >> 4;
    const int dp = g & 15;                    // d-pair
    const int dpb = dp * 4;                   // byte offset within 64B head row

    // SRD over the whole value buffer; voffset = tap byteoff + dpb
    union { const void* p; unsigned int u[2]; } ab; ab.p = (const void*)value;
    int32x4 srd;
    srd.x = (int)ab.u[0];
    srd.y = (int)(ab.u[1] & 0xffffu);         // stride=0, base high bits
    srd.z = (int)(M_ROWS * 512);              // num_records (bytes)
    srd.w = 0x00020000;                       // raw dword access

    f32x2 acc = {0.f, 0.f};
#pragma unroll 4
    for (int lp = 0; lp < 16; ++lp) {
      const int si = h * 17 + lp;
#pragma unroll
      for (int t = 0; t < 4; ++t) {
        const float2 f = s_wo[qi][t][si];
        const unsigned int v = (unsigned int)llvm_amdgcn_raw_buffer_load_i32(
            srd, __float_as_int(f.y) + dpb, 0, 0);
        f32x2 av = {__uint_as_float(v << 16), __uint_as_float(v & 0xffff0000u)};
        acc += f.x * av;
      }
    }
    mid[(size_t)q * 128 + h * 16 + dp] = pk_bf16(acc.x, acc.y);
  }
}

// ---------------------------------------------------------------------------
extern "C" void kernel_launch(void* const* d_in, const int* in_sizes, int n_in,
                              void* d_out, int out_size, void* d_ws,
                              size_t ws_size, hipStream_t stream) {
  const float* query  = (const float*)d_in[0];
  const float* refp   = (const float*)d_in[1];
  const float* inpf   = (const float*)d_in[2];
  const float* W_off  = (const float*)d_in[5];
  const float* b_off  = (const float*)d_in[6];
  const float* W_attn = (const float*)d_in[7];
  const float* b_attn = (const float*)d_in[8];
  const float* W_val  = (const float*)d_in[9];
  const float* b_val  = (const float*)d_in[10];
  const float* W_out  = (const float*)d_in[11];
  const float* b_out  = (const float*)d_in[12];
  float* out = (float*)d_out;

  unsigned char* w = (unsigned char*)d_ws;
  unsigned short* Wval_t = (unsigned short*)w;  w += 256 * 256 * 2;
  unsigned short* Woa_t  = (unsigned short*)w;  w += 384 * 256 * 2;
  unsigned short* Wout_t = (unsigned short*)w;  w += 256 * 256 * 2;
  float*          b_oa   = (float*)w;           w += 384 * 4 + 64;
  unsigned short* v_buf  = (unsigned short*)w;  w += (size_t)M_ROWS * 256 * 2;
  unsigned short* oa_buf = (unsigned short*)w;  w += (size_t)M_ROWS * 384 * 2;
  unsigned int*   mid_buf = (unsigned int*)w;   // M*128 u32

  const dim3 blk(256);
  const int mg = (M_ROWS + 127) / 128;   // 208

  prep_w<<<dim3(896), blk, 0, stream>>>(W_off, b_off, W_attn, b_attn,
                                        W_val, W_out, Wval_t, Woa_t,
                                        Wout_t, b_oa);
  // value -> bf16 ; off|logits -> fp16 (fp32 A, in-register conversion)
  gemm_vo<<<dim3(mg, 5), blk, 0, stream>>>(inpf, query, Wval_t, Woa_t,
                                           b_val, b_oa, v_buf, oa_buf);
  // softmax + bilinear sampling -> mid (bf16 pairs)
  sample_kernel<<<dim3(M_ROWS / 2), blk, 0, stream>>>(refp, oa_buf, v_buf,
                                                      mid_buf);
  // out = mid @ W_out + b_out -> fp32
  gemm_out<<<dim3(mg, 2), blk, 0, stream>>>((const unsigned short*)mid_buf,
                                            Wout_t, b_out, out);
}